// Round 4
// baseline (341.747 us; speedup 1.0000x reference)
//
#include <hip/hip_runtime.h>
#include <hip/hip_bf16.h>

typedef __attribute__((ext_vector_type(8))) short bf16x8;
typedef __attribute__((ext_vector_type(16))) float f32x16;
typedef __attribute__((ext_vector_type(8))) unsigned short u16x8;

__device__ __forceinline__ unsigned short f2bf(float f) {
  union { float f; unsigned u; } c; c.f = f;
  unsigned u = c.u;
  u = (u + 0x7FFFu + ((u >> 16) & 1u)) >> 16;   // RNE
  return (unsigned short)u;
}

__device__ __forceinline__ void gld_lds16(const void* g, void* l) {
  __builtin_amdgcn_global_load_lds(
      (__attribute__((address_space(1))) unsigned int*)g,
      (__attribute__((address_space(3))) unsigned int*)l,
      16, 0, 0);
}

// ---------------- fused conversion + zero kernel ----------------
// [0,4096): x->x16 ; [4096,6144): K->K16 ; [6144,7168): V -> Vt (transpose)
// [7168,9216): zero out (for GEMM2 split-K atomics). First 32 blocks zero lsum.
__global__ void cvt_all(const float* __restrict__ x, unsigned short* __restrict__ x16,
                        const float* __restrict__ Kw, unsigned short* __restrict__ K16,
                        const float* __restrict__ V, unsigned short* __restrict__ Vt,
                        float* __restrict__ lsum, float* __restrict__ outz) {
  const int b = blockIdx.x;
  const int tid = threadIdx.x;
  if (b < 32) lsum[b * 256 + tid] = 0.f;

  if (b < 6144) {
    const float* in;
    unsigned short* out;
    int i;
    if (b < 4096) {
      in = x; out = x16; i = (b * 256 + tid) * 8;
    } else {
      in = Kw; out = K16; i = ((b - 4096) * 256 + tid) * 8;
    }
    const float4* p = (const float4*)(in + i);
    float4 a = p[0], bb = p[1];
    u16x8 r;
    r[0] = f2bf(a.x); r[1] = f2bf(a.y); r[2] = f2bf(a.z); r[3] = f2bf(a.w);
    r[4] = f2bf(bb.x); r[5] = f2bf(bb.y); r[6] = f2bf(bb.z); r[7] = f2bf(bb.w);
    *(u16x8*)(out + i) = r;
  } else if (b < 7168) {
    __shared__ unsigned short t[64][65];
    const int tile = b - 6144;
    const int p0 = (tile & 63) * 64;
    const int e0 = (tile >> 6) * 64;
    const int tx = tid & 63;
    const int ty = tid >> 6;
#pragma unroll
    for (int i = 0; i < 16; ++i) {
      int p = ty + i * 4;
      t[p][tx] = f2bf(V[(size_t)(p0 + p) * 1024 + e0 + tx]);
    }
    __syncthreads();
    const int op = (tid & 7) * 8;
    const int oe = tid >> 3;
#pragma unroll
    for (int h = 0; h < 2; ++h) {
      int e = oe + h * 32;
      u16x8 r;
#pragma unroll
      for (int i = 0; i < 8; ++i) r[i] = t[op + i][e];
      *(u16x8*)(Vt + (size_t)(e0 + e) * 4096 + p0 + op) = r;
    }
  } else {
    // zero 32 MB of out: 2048 blocks x 256 thr x 16 floats
    size_t base = ((size_t)(b - 7168) * 256 + tid) * 16;
    float4 z = {0.f, 0.f, 0.f, 0.f};
#pragma unroll
    for (int k = 0; k < 4; ++k) *(float4*)(outz + base + k * 4) = z;
  }
}

// ------------- 256x128-tile NT GEMM, 4 waves, 32x32x16 MFMA, 2 blocks/CU ----
// A [M x Kd], B [N x Kd] row-major bf16. S = A.B^T over k in [k0, k0+KT*64).
// EPI==0: full K (Kd=1024). P = exp2(scale*S) -> Pout bf16 + row sums -> lsum.
//         grid 1024 (32m x 32n), XCD-swizzled n-fastest.
// EPI==1: split-K halves (Kd=4096, KT=32). atomicAdd(out, S/lin[row]).
//         grid 512 (32m x 8n x 2k), XCD-swizzled, k-halves adjacent.
// Simple m97 structure: 2 syncthreads per K-tile; compiler schedules reads/MFMA;
// overlap comes from the co-resident second block (m114 mechanism).
template <int EPI>
__global__ __launch_bounds__(256, 2) void gemm_tk(
    const unsigned short* __restrict__ A, const unsigned short* __restrict__ B,
    unsigned short* __restrict__ Pout, float* __restrict__ lsum,
    float* __restrict__ Cout, const float* __restrict__ lin, float scale) {
  constexpr int Kd = EPI ? 4096 : 1024;
  constexpr int Nc = EPI ? 1024 : 4096;
  constexpr int KT = EPI ? 32 : 16;       // K-tiles of 64 per block

  __shared__ __align__(16) char lds[49152];   // A: 32 KB, B: 16 KB

  const int tid = threadIdx.x;
  const int lane = tid & 63;
  const int w = tid >> 6;        // 4 waves
  const int wm = w >> 1;         // 0..1
  const int wn = w & 1;          // 0..1
  const int l31 = lane & 31;
  const int q = lane >> 5;       // 0..1

  int m_t, n_t, k0;
  if constexpr (EPI == 0) {
    const int wg = (blockIdx.x & 7) * 128 + (blockIdx.x >> 3);
    n_t = wg & 31; m_t = wg >> 5; k0 = 0;
  } else {
    const int wg = (blockIdx.x & 7) * 64 + (blockIdx.x >> 3);
    k0 = (wg & 1) * 2048; n_t = (wg >> 1) & 7; m_t = wg >> 4;
  }
  const int row0 = m_t * 256;
  const int col0 = n_t * 128;

  // Staging: chunk c = tid + i*256 -> row r = (tid>>3)+i*32, slot s = tid&7.
  // LDS slot s of row r holds global k-chunk s^(r&7); (r&7) is i-invariant.
  const int tr = tid >> 3;                    // 0..31
  const int ss = (tid & 7) ^ (tr & 7);
  const unsigned short* pA = A + (size_t)(row0 + tr) * Kd + k0 + ss * 8;
  const unsigned short* pB = B + (size_t)(col0 + tr) * Kd + k0 + ss * 8;
  char* ldsAw = lds + w * 1024;               // + i*4096 ; HW adds lane*16
  char* ldsBw = lds + 32768 + w * 1024;

  // Fragment reads (32x32x16): A row = wm*128 + mi*32 + l31, k-chunk = ks*2+q.
  // row&7 == lane&7 -> swizzled chunk index = (ks*2+q) ^ (lane&7).
  const char* aBase = lds + (wm * 128 + l31) * 128;
  const char* bBase = lds + 32768 + (wn * 64 + l31) * 128;
  int ccx[4];
#pragma unroll
  for (int ks = 0; ks < 4; ++ks) ccx[ks] = ((ks * 2 + q) ^ (lane & 7)) * 16;

  f32x16 acc[4][2] = {};

  for (int t = 0; t < KT; ++t) {
    __syncthreads();   // prev tile's reads done before overwrite issue
#pragma unroll
    for (int i = 0; i < 8; ++i)
      gld_lds16(pA + (size_t)i * 32 * Kd, ldsAw + i * 4096);
#pragma unroll
    for (int i = 0; i < 4; ++i)
      gld_lds16(pB + (size_t)i * 32 * Kd, ldsBw + i * 4096);
    pA += 64;
    pB += 64;
    __syncthreads();   // staging complete (compiler drains vmcnt before barrier)

#pragma unroll
    for (int ks = 0; ks < 4; ++ks) {
      bf16x8 aF[4], bF[2];
#pragma unroll
      for (int mi = 0; mi < 4; ++mi)
        aF[mi] = *(const bf16x8*)(aBase + mi * 4096 + ccx[ks]);
#pragma unroll
      for (int ni = 0; ni < 2; ++ni)
        bF[ni] = *(const bf16x8*)(bBase + ni * 4096 + ccx[ks]);
#pragma unroll
      for (int mi = 0; mi < 4; ++mi)
#pragma unroll
        for (int ni = 0; ni < 2; ++ni)
          acc[mi][ni] = __builtin_amdgcn_mfma_f32_32x32x16_bf16(
              aF[mi], bF[ni], acc[mi][ni], 0, 0, 0);
    }
  }

  // C/D layout (32x32, verified m74/m101): col = lane&31,
  // row = (reg&3) + 8*(reg>>2) + 4*(lane>>5).
  if constexpr (EPI == 0) {
#pragma unroll
    for (int mi = 0; mi < 4; ++mi) {
#pragma unroll
      for (int j = 0; j < 16; ++j) {
        const int gr = row0 + wm * 128 + mi * 32 + (j & 3) + 8 * (j >> 2) + 4 * q;
        float rsum = 0.f;
#pragma unroll
        for (int ni = 0; ni < 2; ++ni) {
          const int gc = col0 + wn * 64 + ni * 32 + l31;
          float pv = exp2f(acc[mi][ni][j] * scale);  // scale includes log2(e)
          rsum += pv;
          Pout[(size_t)gr * Nc + gc] = f2bf(pv);
        }
        rsum += __shfl_xor(rsum, 1);
        rsum += __shfl_xor(rsum, 2);
        rsum += __shfl_xor(rsum, 4);
        rsum += __shfl_xor(rsum, 8);
        rsum += __shfl_xor(rsum, 16);
        if (l31 == 0) atomicAdd(&lsum[gr], rsum);
      }
    }
  } else {
#pragma unroll
    for (int mi = 0; mi < 4; ++mi) {
#pragma unroll
      for (int j = 0; j < 16; ++j) {
        const int gr = row0 + wm * 128 + mi * 32 + (j & 3) + 8 * (j >> 2) + 4 * q;
        const float rl = 1.0f / lin[gr];
#pragma unroll
        for (int ni = 0; ni < 2; ++ni) {
          const int gc = col0 + wn * 64 + ni * 32 + l31;
          atomicAdd(&Cout[(size_t)gr * Nc + gc], acc[mi][ni][j] * rl);
        }
      }
    }
  }
}

extern "C" void kernel_launch(void* const* d_in, const int* in_sizes, int n_in,
                              void* d_out, int out_size, void* d_ws,
                              size_t ws_size, hipStream_t stream) {
  const float* x = (const float*)d_in[0];   // [8192,1024]
  const float* Kw = (const float*)d_in[1];  // [4096,1024]
  const float* Vw = (const float*)d_in[2];  // [4096,1024]
  float* out = (float*)d_out;               // [8192,1024]
  char* ws = (char*)d_ws;

  unsigned short* x16  = (unsigned short*)(ws);                   // 16 MB
  unsigned short* K16  = (unsigned short*)(ws + (16u << 20));     //  8 MB
  unsigned short* V16t = (unsigned short*)(ws + (24u << 20));     //  8 MB
  float*          lsum = (float*)(ws + (32u << 20));              // 32 KB
  unsigned short* P16  = (unsigned short*)(ws + (33u << 20));     // 64 MB

  cvt_all<<<9216, 256, 0, stream>>>(x, x16, Kw, K16, Vw, V16t, lsum, out);

  // GEMM1: P = exp(x16 . K16^T / 32), row sums -> lsum.
  gemm_tk<0><<<1024, 256, 0, stream>>>(
      x16, K16, P16, lsum, nullptr, nullptr,
      0.03125f * 1.44269504088896340736f);
  // GEMM2 (split-K x2): out += (P16 . V16t^T) / lsum[row]
  gemm_tk<1><<<512, 256, 0, stream>>>(
      P16, V16t, nullptr, nullptr, out, lsum, 0.f);
}